// Round 9
// baseline (291.961 us; speedup 1.0000x reference)
//
#include <hip/hip_runtime.h>

// ---------- types ----------
typedef __attribute__((ext_vector_type(8))) short bf16x8;   // 8 bf16 in 4 VGPRs
typedef __attribute__((ext_vector_type(4))) short bf16x4;   // 4 bf16 in 2 VGPRs
typedef __attribute__((ext_vector_type(4))) float f32x4;    // MFMA C/D

#define MFMA32(a,b,c) __builtin_amdgcn_mfma_f32_16x16x32_bf16((a),(b),(c),0,0,0)
#define MFMA16(a,b,c) __builtin_amdgcn_mfma_f32_16x16x16bf16_1k((a),(b),(c),0,0,0)
#define LOG2E 1.44269504f

#define VMW_(n) asm volatile("s_waitcnt vmcnt(" #n ")" ::: "memory")
#define VMW(n) VMW_(n)

__device__ __forceinline__ unsigned short f2bf(float f) {
  unsigned int u = __float_as_uint(f);
  u += 0x7fffu + ((u >> 16) & 1u);      // round-to-nearest-even
  return (unsigned short)(u >> 16);
}

// async global->LDS, 16B per lane; LDS dest = wave-uniform base + lane*16
__device__ __forceinline__ void cp16(const void* g, void* l) {
  __builtin_amdgcn_global_load_lds((const __attribute__((address_space(1))) void*)g,
                                   (__attribute__((address_space(3))) void*)l, 16, 0, 0);
}

// ---------- fp32 -> bf16 (query, memory) + bias pre-transform, one launch ----
__global__ void conv_both(const float* __restrict__ q, const float* __restrict__ m,
                          const float* __restrict__ bias,
                          unsigned short* __restrict__ qo, unsigned short* __restrict__ mo,
                          float* __restrict__ bz) {
  int i = blockIdx.x * 256 + threadIdx.x;   // grid covers 4718592 + 4096 float4s
  if (i < 524288) {
    float4 v = ((const float4*)q)[i];
    ushort4 o; o.x = f2bf(v.x); o.y = f2bf(v.y); o.z = f2bf(v.z); o.w = f2bf(v.w);
    ((ushort4*)qo)[i] = o;
  } else if (i < 4718592) {
    int j = i - 524288;
    float4 v = ((const float4*)m)[j];
    ushort4 o; o.x = f2bf(v.x); o.y = f2bf(v.y); o.z = f2bf(v.z); o.w = f2bf(v.w);
    ((ushort4*)mo)[j] = o;
  } else {
    int j = i - 4718592;                   // < 4096: bias -> bias*log2e - 16
    float4 v = ((const float4*)bias)[j];
    float4 o;
    o.x = __builtin_fmaf(v.x, LOG2E, -16.f);
    o.y = __builtin_fmaf(v.y, LOG2E, -16.f);
    o.z = __builtin_fmaf(v.z, LOG2E, -16.f);
    o.w = __builtin_fmaf(v.w, LOG2E, -16.f);
    ((float4*)bz)[j] = o;
  }
}

// ---------- 1024x1024 transpose+convert for all 4 weights in one launch ----------
__global__ void transpose4(const float* __restrict__ Wq, const float* __restrict__ Wk,
                           const float* __restrict__ Wv, const float* __restrict__ Wo,
                           unsigned short* __restrict__ dst) {
  __shared__ float t[32][33];
  int z = blockIdx.z;
  const float* W = (z == 0) ? Wq : (z == 1) ? Wk : (z == 2) ? Wv : Wo;
  unsigned short* WT = dst + (size_t)z * 1048576;
  int bx = blockIdx.x * 32, by = blockIdx.y * 32;
  int x = threadIdx.x, y0 = threadIdx.y;
#pragma unroll
  for (int r = 0; r < 4; ++r)
    t[y0 + r * 8][x] = W[(size_t)(by + y0 + r * 8) * 1024 + bx + x];
  __syncthreads();
#pragma unroll
  for (int r = 0; r < 4; ++r)
    WT[(size_t)(bx + y0 + r * 8) * 1024 + by + x] = f2bf(t[x][y0 + r * 8]);
}

// ---------- fused K/V projection — r14: m201-geometry 8-phase 256x256 -------
// Key insight: WkT‖WvT are CONTIGUOUS -> fused KV proj is one plain GEMM
// C[16384][2048] = mbf @ B[2048][1024]^T. Apply the verified 256^2 8-phase
// template: 512 thr (8 waves 2Mx4N), wave-out 128x64, BK=64, LDS 128KB =
// {A,B} x {unit0,unit1} x {par0,par1}, unit = 16KB (2 cp16/thread).
//   A units split by m-bit6 (phase quadrant mh); lds_row=(r>>6)*64+... bijective.
//   B units split by n-half (wave-static); same 8-slot T2 swizzle as A.
// Phases/iter (tiles T=2i par0, T+1 par1); quadrants (mh,kh):
//   ph0 (0,0): W4; stage A1(T+1) | ph1 (1,0): W4; stage B0(T+1)
//   ph2 (0,1):     stage B1(T+1) | ph3 (1,1):     stage B0(T+2)
//   ph4 (0,0)':W2; stage B1(T+2) | ph5 (1,0)':    stage A0(T+2)
//   ph6 (0,1)':    stage A1(T+2) | ph7 (1,1)':    stage A0(T+3)
// FIFO-derived waits (vmcnt in LOADS, 2/unit): every retired load >=3 phases
// old -> waits ~free; never drains. Unit free-windows checked: every stage
// is >=1 barrier after its region's last ds_read. Race (r10 lesson): each
// phase does lgkmcnt(0) BEFORE s_barrier -> a wave's reads complete before
// any wave's next-phase stages can overwrite them. MFMAs (register-only)
// float freely across barriers = the pipeline.
__global__ __launch_bounds__(512, 2) void gemm_kv(
    const unsigned short* __restrict__ A,   // mbf [16384][1024]
    const unsigned short* __restrict__ B,   // [2048][1024] = WkT ‖ WvT
    unsigned short* __restrict__ Kp,        // [16384][1024]
    unsigned short* __restrict__ Vt)        // [1024][16384]
{
  // ushort offsets: A par p: p*16384 (+unit*8192); B: 32768 + p*16384 (+unit*8192)
  __shared__ __attribute__((aligned(16))) unsigned short lds[65536]; // 128 KB
  const int tid = threadIdx.x;
  const int w = tid >> 6, lane = tid & 63;
  const int lh = lane & 15, q4 = lane >> 4;
  const int id = blockIdx.x;
  const int xcd = id & 7, j = id >> 3;            // 64 blocks/XCD
  const int tm = (xcd * 8 + (j >> 3)) * 256;      // 8 m-strips per XCD
  const int tn = (j & 7) * 256;                   // 0..1792 (K half then V half)
  const int wm = (w >> 2) * 128;                  // 0 / 128
  const int bn = (w & 3) * 64;                    // 0/64/128/192

  // fragment-read geometry (8-slot T2 swizzle, row stride 64 ushorts = 128B)
  const int fs0 = ((0 + q4) ^ (lh & 7)) * 8;
  const int fs1 = ((4 + q4) ^ (lh & 7)) * 8;
  const int a_off = (wm >> 7) * 4096 + lh * 64;           // + par*16384 + mh*8192 + mf*1024 + fs
  const int ub = (w >> 1) & 1;                            // B unit owned by wave
  const int b_off = 32768 + ub * 8192 + ((bn & 64) + lh) * 64; // + par*16384 + nf*1024 + fs

  // staging geometry: chunk c of thread covers lds rows r_c = 16w+8c+(lane>>3)
  const int r0 = w * 16 + (lane >> 3), r1 = r0 + 8;
  const int scol = ((lane & 7) ^ ((lane >> 3) & 7)) * 8;  // T2 source swizzle
  const int am0 = (r0 >> 6) * 128 + (r0 & 63);            // A m-interleave map
  const int am1 = (r1 >> 6) * 128 + (r1 & 63);
  const unsigned short* Ag = A + (size_t)tm * 1024 + scol;
  const unsigned short* Bg = B + (size_t)tn * 1024 + scol;
  const int dstc = w * 1024;                              // c=0 chunk; c=1: +512

#define STG_A(T,U) do { \
    cp16(Ag + (size_t)(am0 + (U)*64) * 1024 + (T)*64, lds + (((T)&1)*16384) + (U)*8192 + dstc); \
    cp16(Ag + (size_t)(am1 + (U)*64) * 1024 + (T)*64, lds + (((T)&1)*16384) + (U)*8192 + dstc + 512); \
  } while (0)
#define STG_B(T,U) do { \
    cp16(Bg + (size_t)((U)*128 + r0) * 1024 + (T)*64, lds + 32768 + (((T)&1)*16384) + (U)*8192 + dstc); \
    cp16(Bg + (size_t)((U)*128 + r1) * 1024 + (T)*64, lds + 32768 + (((T)&1)*16384) + (U)*8192 + dstc + 512); \
  } while (0)

  f32x4 acc[8][4] = {};
  bf16x8 afr[4], bfr[4];

#define PHASE(PAR, MH, FS, BL, WC, SC) do {                                   \
    WC;                                                                       \
    asm volatile("s_waitcnt lgkmcnt(0)" ::: "memory");                        \
    asm volatile("s_barrier" ::: "memory");                                   \
    if (BL) {                                                                 \
      _Pragma("unroll") for (int nf = 0; nf < 4; ++nf)                        \
        bfr[nf] = *(const bf16x8*)(lds + b_off + (PAR)*16384 + nf*1024 + (FS)); \
    }                                                                         \
    _Pragma("unroll") for (int mf = 0; mf < 4; ++mf)                          \
      afr[mf] = *(const bf16x8*)(lds + a_off + (PAR)*16384 + (MH)*8192 + mf*1024 + (FS)); \
    SC;                                                                       \
    __builtin_amdgcn_s_setprio(1);                                            \
    _Pragma("unroll") for (int mf = 0; mf < 4; ++mf)                          \
      _Pragma("unroll") for (int nf = 0; nf < 4; ++nf)                        \
        acc[(MH)*4+mf][nf] = MFMA32(afr[mf], bfr[nf], acc[(MH)*4+mf][nf]);    \
    __builtin_amdgcn_s_setprio(0);                                            \
  } while (0)

  // prologue (FIFO order = steady "i-1 ph3..ph7"): B0(0),B1(0),A0(0),A1(0),A0(1)
  STG_B(0, 0); STG_B(0, 1); STG_A(0, 0); STG_A(0, 1); STG_A(1, 0);

  for (int i = 0; i < 7; ++i) {
    const int T = 2 * i;
    PHASE(0, 0, fs0, 1, VMW(4),  STG_A(T + 1, 1));
    PHASE(0, 1, fs0, 0, VMW(4),  STG_B(T + 1, 0));
    PHASE(0, 0, fs1, 1, (void)0, STG_B(T + 1, 1));
    PHASE(0, 1, fs1, 0, (void)0, STG_B(T + 2, 0));
    PHASE(1, 0, fs0, 1, VMW(2),  STG_B(T + 2, 1));
    PHASE(1, 1, fs0, 0, (void)0, STG_A(T + 2, 0));
    PHASE(1, 0, fs1, 1, (void)0, STG_A(T + 2, 1));
    PHASE(1, 1, fs1, 0, (void)0, STG_A(T + 3, 0));
  }
  // tail (T=14): stage only tile-15 remainder; waits re-derived for short FIFO
  PHASE(0, 0, fs0, 1, VMW(4),  STG_A(15, 1));
  PHASE(0, 1, fs0, 0, VMW(4),  STG_B(15, 0));
  PHASE(0, 0, fs1, 1, (void)0, STG_B(15, 1));
  PHASE(0, 1, fs1, 0, (void)0, (void)0);
  PHASE(1, 0, fs0, 1, VMW(0),  (void)0);
  PHASE(1, 1, fs0, 0, (void)0, (void)0);
  PHASE(1, 0, fs1, 1, (void)0, (void)0);
  PHASE(1, 1, fs1, 0, (void)0, (void)0);

#undef PHASE
#undef STG_A
#undef STG_B

  if (tn < 1024) {
    // K-projection block: Kp row-major 2B stores (r4-verified pattern)
#pragma unroll
    for (int am = 0; am < 8; ++am)
#pragma unroll
      for (int nf = 0; nf < 4; ++nf) {
        int row = tm + wm + (am >> 2) * 64 + (am & 3) * 16 + q4 * 4;
        int col = tn + bn + nf * 16 + lh;
#pragma unroll
        for (int e = 0; e < 4; ++e)
          Kp[(size_t)(row + e) * 1024 + col] = f2bf(acc[am][nf][e]);
      }
  } else {
    // V-projection block: transpose via LDS (256x256 bf16 = 128KB, reuse lds)
    __syncthreads();
#pragma unroll
    for (int am = 0; am < 8; ++am)
#pragma unroll
      for (int nf = 0; nf < 4; ++nf) {
        int lrow = wm + (am >> 2) * 64 + (am & 3) * 16 + q4 * 4; // token, +e
        int lcol = bn + nf * 16 + lh;                            // d 0..255
        ushort4 v4;
        v4.x = f2bf(acc[am][nf][0]); v4.y = f2bf(acc[am][nf][1]);
        v4.z = f2bf(acc[am][nf][2]); v4.w = f2bf(acc[am][nf][3]);
        *(ushort4*)(lds + lcol * 256 + (lrow ^ ((lcol & 31) << 3))) = v4;
      }
    __syncthreads();
#pragma unroll
    for (int p = 0; p < 16; ++p) {
      int colg = p * 16 + (tid >> 5);               // 0..255
      int jb = tid & 31;                            // 8-row block of 256
      const unsigned short* src = lds + colg * 256 + ((jb ^ (colg & 31)) << 3);
      *(int4*)(Vt + (size_t)(tn - 1024 + colg) * 16384 + tm + jb * 8) = *(const int4*)src;
    }
  }
}

// ---------- bf16 GEMM 128x64 tile (q-proj, out-proj) ----------
// r12 quad-buffer window (sync per 2 k-steps); r6 T2 swizzle.
__global__ __launch_bounds__(256) void gemm_bt64(
    const unsigned short* __restrict__ A, const unsigned short* __restrict__ B,
    float* __restrict__ Cf, unsigned short* __restrict__ Cb,
    int M, int N, int K, float scale)
{
  // buffer b at b*6144 ushorts: A[128][32]@0, B[64][32]@4096
  __shared__ __attribute__((aligned(16))) unsigned short lds[24576]; // 48 KB
  int w = threadIdx.x >> 6, lane = threadIdx.x & 63;
  int lh = lane & 15, q4 = lane >> 4;
  int tm = blockIdx.y * 128, tn = blockIdx.x * 64;
  int wm = (w & 1) * 64, wn = (w >> 1) * 32;

  int srow = lane >> 2;
  int scol = ((lane & 3) ^ ((lane >> 3) & 3)) << 3;
  int q4s = (q4 ^ ((lh >> 1) & 3)) << 3;

#define STG64(BUF,K0)                                                          \
  {                                                                            \
    _Pragma("unroll") for (int i = 0; i < 2; ++i) {                            \
      int c = w * 2 + i;                                                       \
      cp16(A + (size_t)(tm + c * 16 + srow) * K + (K0) + scol,                 \
           lds + (BUF) * 6144 + c * 512);                                      \
    }                                                                          \
    cp16(B + (size_t)(tn + w * 16 + srow) * K + (K0) + scol,                   \
         lds + (BUF) * 6144 + 4096 + w * 512);                                 \
  }

  f32x4 acc[4][2] = {};
  const int nw = K >> 6;               // windows of 2 k-steps

  STG64(0, 0);
  STG64(1, 32);

  for (int s = 0; s < nw; ++s) {
    __syncthreads();                   // vmcnt(0)+lgkmcnt(0)+s_barrier
    if (s + 1 < nw) {
      STG64((2 * s + 2) & 3, (2 * s + 2) << 5);
      STG64((2 * s + 3) & 3, (2 * s + 3) << 5);
    }
#pragma unroll
    for (int u = 0; u < 2; ++u) {
      const unsigned short* bse = lds + ((2 * s + u) & 3) * 6144;
      bf16x8 afr[4], bfr[2];
#pragma unroll
      for (int r = 0; r < 4; ++r)
        afr[r] = *(const bf16x8*)(bse + (wm + r * 16 + lh) * 32 + q4s);
#pragma unroll
      for (int c = 0; c < 2; ++c)
        bfr[c] = *(const bf16x8*)(bse + 4096 + (wn + c * 16 + lh) * 32 + q4s);
      __builtin_amdgcn_s_setprio(1);
#pragma unroll
      for (int r = 0; r < 4; ++r)
#pragma unroll
        for (int c = 0; c < 2; ++c)
          acc[r][c] = MFMA32(afr[r], bfr[c], acc[r][c]);
      __builtin_amdgcn_s_setprio(0);
    }
  }
#undef STG64

#pragma unroll
  for (int r = 0; r < 4; ++r)
#pragma unroll
    for (int c = 0; c < 2; ++c)
#pragma unroll
      for (int e = 0; e < 4; ++e) {
        int row = tm + wm + r * 16 + q4 * 4 + e;
        int col = tn + wn + c * 16 + lh;
        if (Cb) Cb[(size_t)row * N + col] = f2bf(acc[r][c][e] * scale);
        else    Cf[(size_t)row * N + col] = acc[r][c][e] * scale;
      }
}

// ---------- attention — r13: single-sync double-buffered K/V staging --------
__global__ __launch_bounds__(256) void attn_kernel(
    const unsigned short* __restrict__ Q, const unsigned short* __restrict__ Kp,
    const unsigned short* __restrict__ VT, const float* __restrict__ bz,
    float* __restrict__ po, float* __restrict__ lp)
{
  __shared__ __attribute__((aligned(16))) unsigned short Klds[8192]; // 2 bufs
  __shared__ __attribute__((aligned(16))) unsigned short Vlds[8192]; // 2 bufs
  int w = threadIdx.x >> 6, lane = threadIdx.x & 63;
  int lh = lane & 15, q4 = lane >> 4;

  // XCD swizzle: same-bh blocks land on same XCD (bh & 7 == xcd)
  int id = blockIdx.x;
  int xcd = id & 7, j = id >> 3;
  int ql = j & 7;                   // 8 blocks per bh
  int half = ql & 1, qt = ql >> 1;  // token half, q-tile
  int bh = (j >> 3) * 8 + xcd;
  int b = bh >> 4, h = bh & 15;
  int q0 = qt * 128;
  int t00 = half * 2048;

  const unsigned short* Qb = Q + (size_t)(b * 512 + q0 + w * 32) * 1024 + h * 64;
  const unsigned short* Kb = Kp + (size_t)(b * 4096) * 1024 + h * 64;
  const unsigned short* Vb = VT + (size_t)(h * 64) * 16384 + b * 4096;
  const float* bzg = bz + (size_t)b * 4096;

  // Q B-operand fragments: 2 strips of 16 q-rows
  bf16x8 bq[2][2];
#pragma unroll
  for (int s = 0; s < 2; ++s)
#pragma unroll
    for (int th = 0; th < 2; ++th)
      bq[s][th] = *(const bf16x8*)(Qb + (size_t)(s * 16 + lh) * 1024 + th * 32 + q4 * 8);

  f32x4 oa[2][4] = {};              // O^T accumulators [strip][d-tile]
  float ls[2] = {0.f, 0.f};

  int rl = lane >> 3, blk = lane & 7;
  int sw = ((blk ^ rl) * 8);        // xor-swizzled 8-ushort block offset in source row

  // prologue: stage tile 0 into buf 0
  {
    int t = t00;
#pragma unroll
    for (int r = 0; r < 2; ++r) {
      int seg = r * 4 + w;
      int row = seg * 8 + rl;
      cp16(Kb + (size_t)(t + row) * 1024 + sw, Klds + seg * 512);
      cp16(Vb + (size_t)row * 16384 + t + sw, Vlds + seg * 512);
    }
  }

  for (int ti = 0; ti < 32; ++ti) {
    int t = t00 + ti * 64;
    __syncthreads();                 // vmcnt(0)+lgkmcnt(0)+s_barrier
    if (ti < 31) {
      int t2 = t + 64;
      int bo2 = ((ti + 1) & 1) * 4096;
#pragma unroll
      for (int r = 0; r < 2; ++r) {
        int seg = r * 4 + w;
        int row = seg * 8 + rl;
        cp16(Kb + (size_t)(t2 + row) * 1024 + sw, Klds + bo2 + seg * 512);
        cp16(Vb + (size_t)row * 16384 + t2 + sw, Vlds + bo2 + seg * 512);
      }
    }
    const unsigned short* Kl = Klds + (ti & 1) * 4096;
    const unsigned short* Vl = Vlds + (ti & 1) * 4096;

    // bias (pre-transformed) for this tile's tokens
    float4 bz4[4];
#pragma unroll
    for (int c = 0; c < 4; ++c)
      bz4[c] = *(const float4*)(bzg + t + c * 16 + q4 * 4);

    // K fragments: A[m=tok][k=d], lane m=lh, k=th*32+q4*8..+8
    bf16x8 kf[4][2];
#pragma unroll
    for (int c = 0; c < 4; ++c)
#pragma unroll
      for (int th = 0; th < 2; ++th)
        kf[c][th] = *(const bf16x8*)(Kl + (c * 16 + lh) * 64 + (((th << 2) + q4) ^ (lh & 7)) * 8);
    // V fragments: A[m=d][k=tok], lane m=lh (+c2*16), k=c*16+q4*4..+4
    bf16x4 vf[4][4];
#pragma unroll
    for (int c = 0; c < 4; ++c)
#pragma unroll
      for (int c2 = 0; c2 < 4; ++c2)
        vf[c][c2] = *(const bf16x4*)(Vl + (c2 * 16 + lh) * 64 +
                                     (((c << 1) + (q4 >> 1)) ^ (lh & 7)) * 8 + (q4 & 1) * 4);

#pragma unroll
    for (int s = 0; s < 2; ++s) {
#pragma unroll
      for (int c = 0; c < 4; ++c) {
        f32x4 z = {};
        z = MFMA32(kf[c][0], bq[s][0], z);
        z = MFMA32(kf[c][1], bq[s][1], z);
        float bzf[4] = {bz4[c].x, bz4[c].y, bz4[c].z, bz4[c].w};
        bf16x4 pb;
        float ps = 0.f;
#pragma unroll
        for (int e = 0; e < 4; ++e) {
          float p = __builtin_amdgcn_exp2f(z[e] + bzf[e]);
          ps += p;
          pb[e] = (short)f2bf(p);
        }
        ls[s] += ps;
#pragma unroll
        for (int c2 = 0; c2 < 4; ++c2)
          oa[s][c2] = MFMA16(vf[c][c2], pb, oa[s][c2]);
      }
    }
  }

  // l: lane holds partial for q=lh; reduce across the 4 q4 groups
#pragma unroll
  for (int s = 0; s < 2; ++s) {
    ls[s] += __shfl_xor(ls[s], 16);
    ls[s] += __shfl_xor(ls[s], 32);
  }

  // partial stores: po[half*256 + bh*4+qt][d=64][q=128]
  int sl = bh * 4 + qt;
  float* pslice = po + (size_t)(half * 256 + sl) * 8192;
#pragma unroll
  for (int s = 0; s < 2; ++s) {
    if (q4 == 0) lp[half * 32768 + sl * 128 + w * 32 + s * 16 + lh] = ls[s];
#pragma unroll
    for (int c2 = 0; c2 < 4; ++c2)
#pragma unroll
      for (int e = 0; e < 4; ++e)
        pslice[(c2 * 16 + q4 * 4 + e) * 128 + w * 32 + s * 16 + lh] = oa[s][c2][e];
  }
}

// ---------- merge token-half partials, normalize, pack to bf16 ao ----------
__global__ void norm_kernel(const float* __restrict__ po, const float* __restrict__ lp,
                            unsigned short* __restrict__ ao) {
  int g = blockIdx.x * 256 + threadIdx.x;   // 262144 threads
  int d8 = (g & 7) * 8;
  int rowid = g >> 3;                        // 0..32767 = bh*512 + qt*128 + qcol
  int bh = rowid >> 9, rq = rowid & 511, qt = rq >> 7, qcol = rq & 127;
  int sl = bh * 4 + qt;
  const float* p0 = po + (size_t)sl * 8192;
  const float* p1 = po + (size_t)(256 + sl) * 8192;
  float l = lp[sl * 128 + qcol] + lp[32768 + sl * 128 + qcol];
  float inv = 1.f / l;
  unsigned short o8[8];
#pragma unroll
  for (int k = 0; k < 8; ++k)
    o8[k] = f2bf((p0[(d8 + k) * 128 + qcol] + p1[(d8 + k) * 128 + qcol]) * inv);
  int b = bh >> 4, h = bh & 15;
  unsigned short* dst = ao + (size_t)(b * 512 + qt * 128 + qcol) * 1024 + h * 64 + d8;
  *(ushort4*)dst = *(ushort4*)o8;
  *(ushort4*)(dst + 4) = *(ushort4*)(o8 + 4);
}

// ---------- launch ----------
extern "C" void kernel_launch(void* const* d_in, const int* in_sizes, int n_in,
                              void* d_out, int out_size, void* d_ws, size_t ws_size,
                              hipStream_t stream) {
  const float* query  = (const float*)d_in[0];
  const float* memory = (const float*)d_in[1];
  const float* bias   = (const float*)d_in[2];
  const float* Wq     = (const float*)d_in[3];
  const float* Wk     = (const float*)d_in[4];
  const float* Wv     = (const float*)d_in[5];
  const float* Wo     = (const float*)d_in[6];
  float* out = (float*)d_out;

  unsigned short* ws  = (unsigned short*)d_ws;
  unsigned short* qbf = ws;                       // 2048*1024
  unsigned short* mbf = qbf + 2097152;            // 16384*1024
  unsigned short* WqT = mbf + 16777216;           // 4 x 1024*1024 contiguous
  unsigned short* WkT = WqT + 1048576;
  unsigned short* WvT = WkT + 1048576;
  unsigned short* WoT = WvT + 1048576;
  unsigned short* qp  = WoT + 1048576;            // 2048*1024 (scaled q proj)
  unsigned short* kp  = qp + 2097152;             // 16384*1024
  unsigned short* vT  = kp + 16777216;            // 1024*16384
  unsigned short* ao  = vT + 16777216;            // 2048*1024
  float* bzw = (float*)(ao + 2097152);            // 16384 floats (bias*log2e-16)
  // po/lp alias qbf+mbf (dead after the projection GEMMs)
  float* po = (float*)ws;                         // 512 slices x 8192 floats = 16 MB
  float* lp = po + 4194304;                       // 65536 floats

  conv_both<<<18448, 256, 0, stream>>>(query, memory, bias, qbf, mbf, bzw);
  transpose4<<<dim3(32, 32, 4), dim3(32, 8), 0, stream>>>(Wq, Wk, Wv, Wo, WqT);

  // q = (query@Wq) * (1/8)*log2e   [2048 x 1024]
  gemm_bt64<<<dim3(16, 16), 256, 0, stream>>>(qbf, WqT, nullptr, qp, 2048, 1024, 1024, 0.125f * LOG2E);
  // fused: kp = memory@Wk, vT = (memory@Wv)^T — one 16384x2048x1024 GEMM
  // over B = WkT‖WvT (contiguous), m201-geometry 8-phase schedule
  gemm_kv<<<512, 512, 0, stream>>>(mbf, WkT, kp, vT);

  attn_kernel<<<512, 256, 0, stream>>>(qp, kp, vT, bzw, po, lp);
  norm_kernel<<<1024, 256, 0, stream>>>(po, lp, ao);

  // out = ao @ Wo (fp32 out)
  gemm_bt64<<<dim3(16, 16), 256, 0, stream>>>(ao, WoT, out, nullptr, 2048, 1024, 1024, 1.f);
}

// Round 11
// 288.958 us; speedup vs baseline: 1.0104x; 1.0104x over previous
//
#include <hip/hip_runtime.h>

// ---------- types ----------
typedef __attribute__((ext_vector_type(8))) short bf16x8;   // 8 bf16 in 4 VGPRs
typedef __attribute__((ext_vector_type(4))) short bf16x4;   // 4 bf16 in 2 VGPRs
typedef __attribute__((ext_vector_type(4))) float f32x4;    // MFMA C/D

#define MFMA32(a,b,c) __builtin_amdgcn_mfma_f32_16x16x32_bf16((a),(b),(c),0,0,0)
#define MFMA16(a,b,c) __builtin_amdgcn_mfma_f32_16x16x16bf16_1k((a),(b),(c),0,0,0)
#define LOG2E 1.44269504f

#define VMW_(n) asm volatile("s_waitcnt vmcnt(" #n ")" ::: "memory")
#define VMW(n) VMW_(n)

__device__ __forceinline__ unsigned short f2bf(float f) {
  unsigned int u = __float_as_uint(f);
  u += 0x7fffu + ((u >> 16) & 1u);      // round-to-nearest-even
  return (unsigned short)(u >> 16);
}

// async global->LDS, 16B per lane; LDS dest = wave-uniform base + lane*16
__device__ __forceinline__ void cp16(const void* g, void* l) {
  __builtin_amdgcn_global_load_lds((const __attribute__((address_space(1))) void*)g,
                                   (__attribute__((address_space(3))) void*)l, 16, 0, 0);
}

// ---------- fp32 -> bf16 (query, memory) + bias pre-transform, one launch ----
__global__ void conv_both(const float* __restrict__ q, const float* __restrict__ m,
                          const float* __restrict__ bias,
                          unsigned short* __restrict__ qo, unsigned short* __restrict__ mo,
                          float* __restrict__ bz) {
  int i = blockIdx.x * 256 + threadIdx.x;   // grid covers 4718592 + 4096 float4s
  if (i < 524288) {
    float4 v = ((const float4*)q)[i];
    ushort4 o; o.x = f2bf(v.x); o.y = f2bf(v.y); o.z = f2bf(v.z); o.w = f2bf(v.w);
    ((ushort4*)qo)[i] = o;
  } else if (i < 4718592) {
    int j = i - 524288;
    float4 v = ((const float4*)m)[j];
    ushort4 o; o.x = f2bf(v.x); o.y = f2bf(v.y); o.z = f2bf(v.z); o.w = f2bf(v.w);
    ((ushort4*)mo)[j] = o;
  } else {
    int j = i - 4718592;                   // < 4096: bias -> bias*log2e - 16
    float4 v = ((const float4*)bias)[j];
    float4 o;
    o.x = __builtin_fmaf(v.x, LOG2E, -16.f);
    o.y = __builtin_fmaf(v.y, LOG2E, -16.f);
    o.z = __builtin_fmaf(v.z, LOG2E, -16.f);
    o.w = __builtin_fmaf(v.w, LOG2E, -16.f);
    ((float4*)bz)[j] = o;
  }
}

// ---------- 1024x1024 transpose+convert for all 4 weights in one launch ----------
__global__ void transpose4(const float* __restrict__ Wq, const float* __restrict__ Wk,
                           const float* __restrict__ Wv, const float* __restrict__ Wo,
                           unsigned short* __restrict__ dst) {
  __shared__ float t[32][33];
  int z = blockIdx.z;
  const float* W = (z == 0) ? Wq : (z == 1) ? Wk : (z == 2) ? Wv : Wo;
  unsigned short* WT = dst + (size_t)z * 1048576;
  int bx = blockIdx.x * 32, by = blockIdx.y * 32;
  int x = threadIdx.x, y0 = threadIdx.y;
#pragma unroll
  for (int r = 0; r < 4; ++r)
    t[y0 + r * 8][x] = W[(size_t)(by + y0 + r * 8) * 1024 + bx + x];
  __syncthreads();
#pragma unroll
  for (int r = 0; r < 4; ++r)
    WT[(size_t)(bx + y0 + r * 8) * 1024 + by + x] = f2bf(t[x][y0 + r * 8]);
}

// ---------- fused K/V projection — r14: m201-geometry 8-phase 256x256 -------
// (unchanged; dropped below attn in the profile)
__global__ __launch_bounds__(512, 2) void gemm_kv(
    const unsigned short* __restrict__ A,   // mbf [16384][1024]
    const unsigned short* __restrict__ B,   // [2048][1024] = WkT ‖ WvT
    unsigned short* __restrict__ Kp,        // [16384][1024]
    unsigned short* __restrict__ Vt)        // [1024][16384]
{
  __shared__ __attribute__((aligned(16))) unsigned short lds[65536]; // 128 KB
  const int tid = threadIdx.x;
  const int w = tid >> 6, lane = tid & 63;
  const int lh = lane & 15, q4 = lane >> 4;
  const int id = blockIdx.x;
  const int xcd = id & 7, j = id >> 3;            // 64 blocks/XCD
  const int tm = (xcd * 8 + (j >> 3)) * 256;      // 8 m-strips per XCD
  const int tn = (j & 7) * 256;                   // 0..1792 (K half then V half)
  const int wm = (w >> 2) * 128;                  // 0 / 128
  const int bn = (w & 3) * 64;                    // 0/64/128/192

  const int fs0 = ((0 + q4) ^ (lh & 7)) * 8;
  const int fs1 = ((4 + q4) ^ (lh & 7)) * 8;
  const int a_off = (wm >> 7) * 4096 + lh * 64;
  const int ub = (w >> 1) & 1;
  const int b_off = 32768 + ub * 8192 + ((bn & 64) + lh) * 64;

  const int r0 = w * 16 + (lane >> 3), r1 = r0 + 8;
  const int scol = ((lane & 7) ^ ((lane >> 3) & 7)) * 8;
  const int am0 = (r0 >> 6) * 128 + (r0 & 63);
  const int am1 = (r1 >> 6) * 128 + (r1 & 63);
  const unsigned short* Ag = A + (size_t)tm * 1024 + scol;
  const unsigned short* Bg = B + (size_t)tn * 1024 + scol;
  const int dstc = w * 1024;

#define STG_A(T,U) do { \
    cp16(Ag + (size_t)(am0 + (U)*64) * 1024 + (T)*64, lds + (((T)&1)*16384) + (U)*8192 + dstc); \
    cp16(Ag + (size_t)(am1 + (U)*64) * 1024 + (T)*64, lds + (((T)&1)*16384) + (U)*8192 + dstc + 512); \
  } while (0)
#define STG_B(T,U) do { \
    cp16(Bg + (size_t)((U)*128 + r0) * 1024 + (T)*64, lds + 32768 + (((T)&1)*16384) + (U)*8192 + dstc); \
    cp16(Bg + (size_t)((U)*128 + r1) * 1024 + (T)*64, lds + 32768 + (((T)&1)*16384) + (U)*8192 + dstc + 512); \
  } while (0)

  f32x4 acc[8][4] = {};
  bf16x8 afr[4], bfr[4];

#define PHASE(PAR, MH, FS, BL, WC, SC) do {                                   \
    WC;                                                                       \
    asm volatile("s_waitcnt lgkmcnt(0)" ::: "memory");                        \
    asm volatile("s_barrier" ::: "memory");                                   \
    if (BL) {                                                                 \
      _Pragma("unroll") for (int nf = 0; nf < 4; ++nf)                        \
        bfr[nf] = *(const bf16x8*)(lds + b_off + (PAR)*16384 + nf*1024 + (FS)); \
    }                                                                         \
    _Pragma("unroll") for (int mf = 0; mf < 4; ++mf)                          \
      afr[mf] = *(const bf16x8*)(lds + a_off + (PAR)*16384 + (MH)*8192 + mf*1024 + (FS)); \
    SC;                                                                       \
    __builtin_amdgcn_s_setprio(1);                                            \
    _Pragma("unroll") for (int mf = 0; mf < 4; ++mf)                          \
      _Pragma("unroll") for (int nf = 0; nf < 4; ++nf)                        \
        acc[(MH)*4+mf][nf] = MFMA32(afr[mf], bfr[nf], acc[(MH)*4+mf][nf]);    \
    __builtin_amdgcn_s_setprio(0);                                            \
  } while (0)

  // prologue (FIFO order = steady "i-1 ph3..ph7"): B0(0),B1(0),A0(0),A1(0),A0(1)
  STG_B(0, 0); STG_B(0, 1); STG_A(0, 0); STG_A(0, 1); STG_A(1, 0);

  for (int i = 0; i < 7; ++i) {
    const int T = 2 * i;
    PHASE(0, 0, fs0, 1, VMW(4),  STG_A(T + 1, 1));
    PHASE(0, 1, fs0, 0, VMW(4),  STG_B(T + 1, 0));
    PHASE(0, 0, fs1, 1, (void)0, STG_B(T + 1, 1));
    PHASE(0, 1, fs1, 0, (void)0, STG_B(T + 2, 0));
    PHASE(1, 0, fs0, 1, VMW(2),  STG_B(T + 2, 1));
    PHASE(1, 1, fs0, 0, (void)0, STG_A(T + 2, 0));
    PHASE(1, 0, fs1, 1, (void)0, STG_A(T + 2, 1));
    PHASE(1, 1, fs1, 0, (void)0, STG_A(T + 3, 0));
  }
  PHASE(0, 0, fs0, 1, VMW(4),  STG_A(15, 1));
  PHASE(0, 1, fs0, 0, VMW(4),  STG_B(15, 0));
  PHASE(0, 0, fs1, 1, (void)0, STG_B(15, 1));
  PHASE(0, 1, fs1, 0, (void)0, (void)0);
  PHASE(1, 0, fs0, 1, VMW(0),  (void)0);
  PHASE(1, 1, fs0, 0, (void)0, (void)0);
  PHASE(1, 0, fs1, 1, (void)0, (void)0);
  PHASE(1, 1, fs1, 0, (void)0, (void)0);

#undef PHASE
#undef STG_A
#undef STG_B

  if (tn < 1024) {
#pragma unroll
    for (int am = 0; am < 8; ++am)
#pragma unroll
      for (int nf = 0; nf < 4; ++nf) {
        int row = tm + wm + (am >> 2) * 64 + (am & 3) * 16 + q4 * 4;
        int col = tn + bn + nf * 16 + lh;
#pragma unroll
        for (int e = 0; e < 4; ++e)
          Kp[(size_t)(row + e) * 1024 + col] = f2bf(acc[am][nf][e]);
      }
  } else {
    __syncthreads();
#pragma unroll
    for (int am = 0; am < 8; ++am)
#pragma unroll
      for (int nf = 0; nf < 4; ++nf) {
        int lrow = wm + (am >> 2) * 64 + (am & 3) * 16 + q4 * 4;
        int lcol = bn + nf * 16 + lh;
        ushort4 v4;
        v4.x = f2bf(acc[am][nf][0]); v4.y = f2bf(acc[am][nf][1]);
        v4.z = f2bf(acc[am][nf][2]); v4.w = f2bf(acc[am][nf][3]);
        *(ushort4*)(lds + lcol * 256 + (lrow ^ ((lcol & 31) << 3))) = v4;
      }
    __syncthreads();
#pragma unroll
    for (int p = 0; p < 16; ++p) {
      int colg = p * 16 + (tid >> 5);
      int jb = tid & 31;
      const unsigned short* src = lds + colg * 256 + ((jb ^ (colg & 31)) << 3);
      *(int4*)(Vt + (size_t)(tn - 1024 + colg) * 16384 + tm + jb * 8) = *(const int4*)src;
    }
  }
}

// ---------- bf16 GEMM 128x64 tile (q-proj, out-proj) ----------
// r12 quad-buffer window (sync per 2 k-steps); r6 T2 swizzle.
__global__ __launch_bounds__(256) void gemm_bt64(
    const unsigned short* __restrict__ A, const unsigned short* __restrict__ B,
    float* __restrict__ Cf, unsigned short* __restrict__ Cb,
    int M, int N, int K, float scale)
{
  __shared__ __attribute__((aligned(16))) unsigned short lds[24576]; // 48 KB
  int w = threadIdx.x >> 6, lane = threadIdx.x & 63;
  int lh = lane & 15, q4 = lane >> 4;
  int tm = blockIdx.y * 128, tn = blockIdx.x * 64;
  int wm = (w & 1) * 64, wn = (w >> 1) * 32;

  int srow = lane >> 2;
  int scol = ((lane & 3) ^ ((lane >> 3) & 3)) << 3;
  int q4s = (q4 ^ ((lh >> 1) & 3)) << 3;

#define STG64(BUF,K0)                                                          \
  {                                                                            \
    _Pragma("unroll") for (int i = 0; i < 2; ++i) {                            \
      int c = w * 2 + i;                                                       \
      cp16(A + (size_t)(tm + c * 16 + srow) * K + (K0) + scol,                 \
           lds + (BUF) * 6144 + c * 512);                                      \
    }                                                                          \
    cp16(B + (size_t)(tn + w * 16 + srow) * K + (K0) + scol,                   \
         lds + (BUF) * 6144 + 4096 + w * 512);                                 \
  }

  f32x4 acc[4][2] = {};
  const int nw = K >> 6;               // windows of 2 k-steps

  STG64(0, 0);
  STG64(1, 32);

  for (int s = 0; s < nw; ++s) {
    __syncthreads();                   // vmcnt(0)+lgkmcnt(0)+s_barrier
    if (s + 1 < nw) {
      STG64((2 * s + 2) & 3, (2 * s + 2) << 5);
      STG64((2 * s + 3) & 3, (2 * s + 3) << 5);
    }
#pragma unroll
    for (int u = 0; u < 2; ++u) {
      const unsigned short* bse = lds + ((2 * s + u) & 3) * 6144;
      bf16x8 afr[4], bfr[2];
#pragma unroll
      for (int r = 0; r < 4; ++r)
        afr[r] = *(const bf16x8*)(bse + (wm + r * 16 + lh) * 32 + q4s);
#pragma unroll
      for (int c = 0; c < 2; ++c)
        bfr[c] = *(const bf16x8*)(bse + 4096 + (wn + c * 16 + lh) * 32 + q4s);
      __builtin_amdgcn_s_setprio(1);
#pragma unroll
      for (int r = 0; r < 4; ++r)
#pragma unroll
        for (int c = 0; c < 2; ++c)
          acc[r][c] = MFMA32(afr[r], bfr[c], acc[r][c]);
      __builtin_amdgcn_s_setprio(0);
    }
  }
#undef STG64

#pragma unroll
  for (int r = 0; r < 4; ++r)
#pragma unroll
    for (int c = 0; c < 2; ++c)
#pragma unroll
      for (int e = 0; e < 4; ++e) {
        int row = tm + wm + r * 16 + q4 * 4 + e;
        int col = tn + wn + c * 16 + lh;
        if (Cb) Cb[(size_t)row * N + col] = f2bf(acc[r][c][e] * scale);
        else    Cf[(size_t)row * N + col] = acc[r][c][e] * scale;
      }
}

// ---------- attention — r16: 4-way token split + bias-init (cvt_pk REVERTED)
// r15 NaN triage: of the 3 changes, only the hand-written v_cvt_pk_bf16_f32
// asm can inject arbitrary bit patterns (bf16 exp=0xFF = NaN -> MFMA16
// propagates). Bias-init is linear-identical; split indexing re-derived as
// bijective + fully covered. So: revert pack to proven f2bf; keep split +
// bias-init. If NaN persists, the split is implicated (revert next).
__global__ __launch_bounds__(256) void attn_kernel(
    const unsigned short* __restrict__ Q, const unsigned short* __restrict__ Kp,
    const unsigned short* __restrict__ VT, const float* __restrict__ bz,
    float* __restrict__ po, float* __restrict__ lp)
{
  __shared__ __attribute__((aligned(16))) unsigned short Klds[8192]; // 2 bufs
  __shared__ __attribute__((aligned(16))) unsigned short Vlds[8192]; // 2 bufs
  int w = threadIdx.x >> 6, lane = threadIdx.x & 63;
  int lh = lane & 15, q4 = lane >> 4;

  // XCD swizzle: same-bh blocks land on same XCD (bh & 7 == xcd)
  int id = blockIdx.x;                // 0..1023
  int xcd = id & 7, j = id >> 3;      // j: 0..127
  int ql = j & 15;                    // 16 blocks per bh
  int qrt = ql & 3;                   // token quarter (0..3)
  int qt = ql >> 2;                   // q-tile (0..3)
  int bh = (j >> 4) * 8 + xcd;        // 0..63
  int b = bh >> 4, h = bh & 15;
  int q0 = qt * 128;
  int t00 = qrt * 1024;               // 16 tiles of 64 tokens

  const unsigned short* Qb = Q + (size_t)(b * 512 + q0 + w * 32) * 1024 + h * 64;
  const unsigned short* Kb = Kp + (size_t)(b * 4096) * 1024 + h * 64;
  const unsigned short* Vb = VT + (size_t)(h * 64) * 16384 + b * 4096;
  const float* bzg = bz + (size_t)b * 4096;

  // Q B-operand fragments: 2 strips of 16 q-rows
  bf16x8 bq[2][2];
#pragma unroll
  for (int s = 0; s < 2; ++s)
#pragma unroll
    for (int th = 0; th < 2; ++th)
      bq[s][th] = *(const bf16x8*)(Qb + (size_t)(s * 16 + lh) * 1024 + th * 32 + q4 * 8);

  f32x4 oa[2][4] = {};              // O^T accumulators [strip][d-tile]
  float ls[2] = {0.f, 0.f};

  int rl = lane >> 3, blk = lane & 7;
  int sw = ((blk ^ rl) * 8);        // xor-swizzled 8-ushort block offset in source row

  // prologue: stage tile 0 into buf 0
  {
    int t = t00;
#pragma unroll
    for (int r = 0; r < 2; ++r) {
      int seg = r * 4 + w;
      int row = seg * 8 + rl;
      cp16(Kb + (size_t)(t + row) * 1024 + sw, Klds + seg * 512);
      cp16(Vb + (size_t)row * 16384 + t + sw, Vlds + seg * 512);
    }
  }

  for (int ti = 0; ti < 16; ++ti) {
    int t = t00 + ti * 64;
    __syncthreads();                 // vmcnt(0)+lgkmcnt(0)+s_barrier
    if (ti < 15) {
      int t2 = t + 64;
      int bo2 = ((ti + 1) & 1) * 4096;
#pragma unroll
      for (int r = 0; r < 2; ++r) {
        int seg = r * 4 + w;
        int row = seg * 8 + rl;
        cp16(Kb + (size_t)(t2 + row) * 1024 + sw, Klds + bo2 + seg * 512);
        cp16(Vb + (size_t)row * 16384 + t2 + sw, Vlds + bo2 + seg * 512);
      }
    }
    const unsigned short* Kl = Klds + (ti & 1) * 4096;
    const unsigned short* Vl = Vlds + (ti & 1) * 4096;

    // bias (pre-transformed) for this tile's tokens
    float4 bz4[4];
#pragma unroll
    for (int c = 0; c < 4; ++c)
      bz4[c] = *(const float4*)(bzg + t + c * 16 + q4 * 4);

    // K fragments: A[m=tok][k=d], lane m=lh, k=th*32+q4*8..+8
    bf16x8 kf[4][2];
#pragma unroll
    for (int c = 0; c < 4; ++c)
#pragma unroll
      for (int th = 0; th < 2; ++th)
        kf[c][th] = *(const bf16x8*)(Kl + (c * 16 + lh) * 64 + (((th << 2) + q4) ^ (lh & 7)) * 8);
    // V fragments: A[m=d][k=tok], lane m=lh (+c2*16), k=c*16+q4*4..+4
    bf16x4 vf[4][4];
#pragma unroll
    for (int c = 0; c < 4; ++c)
#pragma unroll
      for (int c2 = 0; c2 < 4; ++c2)
        vf[c][c2] = *(const bf16x4*)(Vl + (c2 * 16 + lh) * 64 +
                                     (((c << 1) + (q4 >> 1)) ^ (lh & 7)) * 8 + (q4 & 1) * 4);

#pragma unroll
    for (int s = 0; s < 2; ++s) {
#pragma unroll
      for (int c = 0; c < 4; ++c) {
        // bias-init accumulator: z = bias (element e = token q4*4+e of group c)
        f32x4 z = {bz4[c].x, bz4[c].y, bz4[c].z, bz4[c].w};
        z = MFMA32(kf[c][0], bq[s][0], z);
        z = MFMA32(kf[c][1], bq[s][1], z);
        bf16x4 pb;
        float ps = 0.f;
#pragma unroll
        for (int e = 0; e < 4; ++e) {
          float p = __builtin_amdgcn_exp2f(z[e]);
          ps += p;
          pb[e] = (short)f2bf(p);
        }
        ls[s] += ps;
#pragma unroll
        for (int c2 = 0; c2 < 4; ++c2)
          oa[s][c2] = MFMA16(vf[c][c2], pb, oa[s][c2]);
      }
    }
  }

  // l: lane holds partial for q=lh; reduce across the 4 q4 groups
#pragma unroll
  for (int s = 0; s < 2; ++s) {
    ls[s] += __shfl_xor(ls[s], 16);
    ls[s] += __shfl_xor(ls[s], 32);
  }

  // partial stores: po[qrt*256 + bh*4+qt][d=64][q=128]
  int sl = bh * 4 + qt;
  float* pslice = po + (size_t)(qrt * 256 + sl) * 8192;
#pragma unroll
  for (int s = 0; s < 2; ++s) {
    if (q4 == 0) lp[qrt * 32768 + sl * 128 + w * 32 + s * 16 + lh] = ls[s];
#pragma unroll
    for (int c2 = 0; c2 < 4; ++c2)
#pragma unroll
      for (int e = 0; e < 4; ++e)
        pslice[(c2 * 16 + q4 * 4 + e) * 128 + w * 32 + s * 16 + lh] = oa[s][c2][e];
  }
}

// ---------- merge 4 token-quarter partials, normalize, pack to bf16 ao ------
__global__ void norm_kernel(const float* __restrict__ po, const float* __restrict__ lp,
                            unsigned short* __restrict__ ao) {
  int g = blockIdx.x * 256 + threadIdx.x;   // 262144 threads
  int d8 = (g & 7) * 8;
  int rowid = g >> 3;                        // 0..32767 = bh*512 + qt*128 + qcol
  int bh = rowid >> 9, rq = rowid & 511, qt = rq >> 7, qcol = rq & 127;
  int sl = bh * 4 + qt;
  const float* p0 = po + (size_t)sl * 8192;
  const float* p1 = po + (size_t)(256 + sl) * 8192;
  const float* p2 = po + (size_t)(512 + sl) * 8192;
  const float* p3 = po + (size_t)(768 + sl) * 8192;
  float l = (lp[sl * 128 + qcol] + lp[32768 + sl * 128 + qcol]) +
            (lp[65536 + sl * 128 + qcol] + lp[98304 + sl * 128 + qcol]);
  float inv = 1.f / l;
  unsigned short o8[8];
#pragma unroll
  for (int k = 0; k < 8; ++k) {
    int o = (d8 + k) * 128 + qcol;
    o8[k] = f2bf(((p0[o] + p1[o]) + (p2[o] + p3[o])) * inv);
  }
  int b = bh >> 4, h = bh & 15;
  unsigned short* dst = ao + (size_t)(b * 512 + qt * 128 + qcol) * 1024 + h * 64 + d8;
  *(ushort4*)dst = *(ushort4*)o8;
  *(ushort4*)(dst + 4) = *(ushort4*)(o8 + 4);
}

// ---------- launch ----------
extern "C" void kernel_launch(void* const* d_in, const int* in_sizes, int n_in,
                              void* d_out, int out_size, void* d_ws, size_t ws_size,
                              hipStream_t stream) {
  const float* query  = (const float*)d_in[0];
  const float* memory = (const float*)d_in[1];
  const float* bias   = (const float*)d_in[2];
  const float* Wq     = (const float*)d_in[3];
  const float* Wk     = (const float*)d_in[4];
  const float* Wv     = (const float*)d_in[5];
  const float* Wo     = (const float*)d_in[6];
  float* out = (float*)d_out;

  unsigned short* ws  = (unsigned short*)d_ws;
  unsigned short* qbf = ws;                       // 2048*1024
  unsigned short* mbf = qbf + 2097152;            // 16384*1024
  unsigned short* WqT = mbf + 16777216;           // 4 x 1024*1024 contiguous
  unsigned short* WkT = WqT + 1048576;
  unsigned short* WvT = WkT + 1048576;
  unsigned short* WoT = WvT + 1048576;
  unsigned short* qp  = WoT + 1048576;            // 2048*1024 (scaled q proj)
  unsigned short* kp  = qp + 2097152;             // 16384*1024
  unsigned short* vT  = kp + 16777216;            // 1024*16384
  unsigned short* ao  = vT + 16777216;            // 2048*1024
  float* bzw = (float*)(ao + 2097152);            // 16384 floats (bias*log2e-16)
  // po/lp alias qbf+mbf (dead after the projection GEMMs):
  // po = 1024 slices x 8192 floats = 32 MB; lp = 131072 floats; 32.5 <= 36 MB.
  float* po = (float*)ws;
  float* lp = po + 8388608;

  conv_both<<<18448, 256, 0, stream>>>(query, memory, bias, qbf, mbf, bzw);
  transpose4<<<dim3(32, 32, 4), dim3(32, 8), 0, stream>>>(Wq, Wk, Wv, Wo, WqT);

  // q = (query@Wq) * (1/8)*log2e   [2048 x 1024]
  gemm_bt64<<<dim3(16, 16), 256, 0, stream>>>(qbf, WqT, nullptr, qp, 2048, 1024, 1024, 0.125f * LOG2E);
  // fused: kp = memory@Wk, vT = (memory@Wv)^T — one 16384x2048x1024 GEMM
  gemm_kv<<<512, 512, 0, stream>>>(mbf, WkT, kp, vT);

  attn_kernel<<<1024, 256, 0, stream>>>(qp, kp, vT, bzw, po, lp);
  norm_kernel<<<1024, 256, 0, stream>>>(po, lp, ao);

  // out = ao @ Wo (fp32 out)
  gemm_bt64<<<dim3(16, 16), 256, 0, stream>>>(ao, WoT, out, nullptr, 2048, 1024, 1024, 1.f);
}

// Round 12
// 286.760 us; speedup vs baseline: 1.0181x; 1.0077x over previous
//
#include <hip/hip_runtime.h>

// ---------- types ----------
typedef __attribute__((ext_vector_type(8))) short bf16x8;   // 8 bf16 in 4 VGPRs
typedef __attribute__((ext_vector_type(4))) short bf16x4;   // 4 bf16 in 2 VGPRs
typedef __attribute__((ext_vector_type(4))) float f32x4;    // MFMA C/D

#define MFMA32(a,b,c) __builtin_amdgcn_mfma_f32_16x16x32_bf16((a),(b),(c),0,0,0)
#define MFMA16(a,b,c) __builtin_amdgcn_mfma_f32_16x16x16bf16_1k((a),(b),(c),0,0,0)
#define LOG2E 1.44269504f

#define VMW_(n) asm volatile("s_waitcnt vmcnt(" #n ")" ::: "memory")
#define VMW(n) VMW_(n)

__device__ __forceinline__ unsigned short f2bf(float f) {
  unsigned int u = __float_as_uint(f);
  u += 0x7fffu + ((u >> 16) & 1u);      // round-to-nearest-even
  return (unsigned short)(u >> 16);
}

// hardware bf16 convert: fptrunc (RNE) -> compiler emits v_cvt_pk_bf16_f32
// for pairs (m240: use the cast, never hand-write the asm).
__device__ __forceinline__ short f2bf_hw(float f) {
  __bf16 b = (__bf16)f;
  return __builtin_bit_cast(short, b);
}

// async global->LDS, 16B per lane; LDS dest = wave-uniform base + lane*16
__device__ __forceinline__ void cp16(const void* g, void* l) {
  __builtin_amdgcn_global_load_lds((const __attribute__((address_space(1))) void*)g,
                                   (__attribute__((address_space(3))) void*)l, 16, 0, 0);
}

// ---------- fp32 -> bf16 (query, memory) + bias pre-transform, one launch ----
__global__ void conv_both(const float* __restrict__ q, const float* __restrict__ m,
                          const float* __restrict__ bias,
                          unsigned short* __restrict__ qo, unsigned short* __restrict__ mo,
                          float* __restrict__ bz) {
  int i = blockIdx.x * 256 + threadIdx.x;   // grid covers 4718592 + 4096 float4s
  if (i < 524288) {
    float4 v = ((const float4*)q)[i];
    ushort4 o; o.x = f2bf(v.x); o.y = f2bf(v.y); o.z = f2bf(v.z); o.w = f2bf(v.w);
    ((ushort4*)qo)[i] = o;
  } else if (i < 4718592) {
    int j = i - 524288;
    float4 v = ((const float4*)m)[j];
    ushort4 o; o.x = f2bf(v.x); o.y = f2bf(v.y); o.z = f2bf(v.z); o.w = f2bf(v.w);
    ((ushort4*)mo)[j] = o;
  } else {
    int j = i - 4718592;                   // < 4096: bias -> bias*log2e - 16
    float4 v = ((const float4*)bias)[j];
    float4 o;
    o.x = __builtin_fmaf(v.x, LOG2E, -16.f);
    o.y = __builtin_fmaf(v.y, LOG2E, -16.f);
    o.z = __builtin_fmaf(v.z, LOG2E, -16.f);
    o.w = __builtin_fmaf(v.w, LOG2E, -16.f);
    ((float4*)bz)[j] = o;
  }
}

// ---------- 1024x1024 transpose+convert for all 4 weights in one launch ----------
__global__ void transpose4(const float* __restrict__ Wq, const float* __restrict__ Wk,
                           const float* __restrict__ Wv, const float* __restrict__ Wo,
                           unsigned short* __restrict__ dst) {
  __shared__ float t[32][33];
  int z = blockIdx.z;
  const float* W = (z == 0) ? Wq : (z == 1) ? Wk : (z == 2) ? Wv : Wo;
  unsigned short* WT = dst + (size_t)z * 1048576;
  int bx = blockIdx.x * 32, by = blockIdx.y * 32;
  int x = threadIdx.x, y0 = threadIdx.y;
#pragma unroll
  for (int r = 0; r < 4; ++r)
    t[y0 + r * 8][x] = W[(size_t)(by + y0 + r * 8) * 1024 + bx + x];
  __syncthreads();
#pragma unroll
  for (int r = 0; r < 4; ++r)
    WT[(size_t)(bx + y0 + r * 8) * 1024 + by + x] = f2bf(t[x][y0 + r * 8]);
}

// ---------- fused K/V projection — r14: m201-geometry 8-phase 256x256 -------
// (unchanged; below attn in the profile)
__global__ __launch_bounds__(512, 2) void gemm_kv(
    const unsigned short* __restrict__ A,   // mbf [16384][1024]
    const unsigned short* __restrict__ B,   // [2048][1024] = WkT ‖ WvT
    unsigned short* __restrict__ Kp,        // [16384][1024]
    unsigned short* __restrict__ Vt)        // [1024][16384]
{
  __shared__ __attribute__((aligned(16))) unsigned short lds[65536]; // 128 KB
  const int tid = threadIdx.x;
  const int w = tid >> 6, lane = tid & 63;
  const int lh = lane & 15, q4 = lane >> 4;
  const int id = blockIdx.x;
  const int xcd = id & 7, j = id >> 3;            // 64 blocks/XCD
  const int tm = (xcd * 8 + (j >> 3)) * 256;      // 8 m-strips per XCD
  const int tn = (j & 7) * 256;                   // 0..1792 (K half then V half)
  const int wm = (w >> 2) * 128;                  // 0 / 128
  const int bn = (w & 3) * 64;                    // 0/64/128/192

  const int fs0 = ((0 + q4) ^ (lh & 7)) * 8;
  const int fs1 = ((4 + q4) ^ (lh & 7)) * 8;
  const int a_off = (wm >> 7) * 4096 + lh * 64;
  const int ub = (w >> 1) & 1;
  const int b_off = 32768 + ub * 8192 + ((bn & 64) + lh) * 64;

  const int r0 = w * 16 + (lane >> 3), r1 = r0 + 8;
  const int scol = ((lane & 7) ^ ((lane >> 3) & 7)) * 8;
  const int am0 = (r0 >> 6) * 128 + (r0 & 63);
  const int am1 = (r1 >> 6) * 128 + (r1 & 63);
  const unsigned short* Ag = A + (size_t)tm * 1024 + scol;
  const unsigned short* Bg = B + (size_t)tn * 1024 + scol;
  const int dstc = w * 1024;

#define STG_A(T,U) do { \
    cp16(Ag + (size_t)(am0 + (U)*64) * 1024 + (T)*64, lds + (((T)&1)*16384) + (U)*8192 + dstc); \
    cp16(Ag + (size_t)(am1 + (U)*64) * 1024 + (T)*64, lds + (((T)&1)*16384) + (U)*8192 + dstc + 512); \
  } while (0)
#define STG_B(T,U) do { \
    cp16(Bg + (size_t)((U)*128 + r0) * 1024 + (T)*64, lds + 32768 + (((T)&1)*16384) + (U)*8192 + dstc); \
    cp16(Bg + (size_t)((U)*128 + r1) * 1024 + (T)*64, lds + 32768 + (((T)&1)*16384) + (U)*8192 + dstc + 512); \
  } while (0)

  f32x4 acc[8][4] = {};
  bf16x8 afr[4], bfr[4];

#define PHASE(PAR, MH, FS, BL, WC, SC) do {                                   \
    WC;                                                                       \
    asm volatile("s_waitcnt lgkmcnt(0)" ::: "memory");                        \
    asm volatile("s_barrier" ::: "memory");                                   \
    if (BL) {                                                                 \
      _Pragma("unroll") for (int nf = 0; nf < 4; ++nf)                        \
        bfr[nf] = *(const bf16x8*)(lds + b_off + (PAR)*16384 + nf*1024 + (FS)); \
    }                                                                         \
    _Pragma("unroll") for (int mf = 0; mf < 4; ++mf)                          \
      afr[mf] = *(const bf16x8*)(lds + a_off + (PAR)*16384 + (MH)*8192 + mf*1024 + (FS)); \
    SC;                                                                       \
    __builtin_amdgcn_s_setprio(1);                                            \
    _Pragma("unroll") for (int mf = 0; mf < 4; ++mf)                          \
      _Pragma("unroll") for (int nf = 0; nf < 4; ++nf)                        \
        acc[(MH)*4+mf][nf] = MFMA32(afr[mf], bfr[nf], acc[(MH)*4+mf][nf]);    \
    __builtin_amdgcn_s_setprio(0);                                            \
  } while (0)

  // prologue (FIFO order = steady "i-1 ph3..ph7"): B0(0),B1(0),A0(0),A1(0),A0(1)
  STG_B(0, 0); STG_B(0, 1); STG_A(0, 0); STG_A(0, 1); STG_A(1, 0);

  for (int i = 0; i < 7; ++i) {
    const int T = 2 * i;
    PHASE(0, 0, fs0, 1, VMW(4),  STG_A(T + 1, 1));
    PHASE(0, 1, fs0, 0, VMW(4),  STG_B(T + 1, 0));
    PHASE(0, 0, fs1, 1, (void)0, STG_B(T + 1, 1));
    PHASE(0, 1, fs1, 0, (void)0, STG_B(T + 2, 0));
    PHASE(1, 0, fs0, 1, VMW(2),  STG_B(T + 2, 1));
    PHASE(1, 1, fs0, 0, (void)0, STG_A(T + 2, 0));
    PHASE(1, 0, fs1, 1, (void)0, STG_A(T + 2, 1));
    PHASE(1, 1, fs1, 0, (void)0, STG_A(T + 3, 0));
  }
  PHASE(0, 0, fs0, 1, VMW(4),  STG_A(15, 1));
  PHASE(0, 1, fs0, 0, VMW(4),  STG_B(15, 0));
  PHASE(0, 0, fs1, 1, (void)0, STG_B(15, 1));
  PHASE(0, 1, fs1, 0, (void)0, (void)0);
  PHASE(1, 0, fs0, 1, VMW(0),  (void)0);
  PHASE(1, 1, fs0, 0, (void)0, (void)0);
  PHASE(1, 0, fs1, 1, (void)0, (void)0);
  PHASE(1, 1, fs1, 0, (void)0, (void)0);

#undef PHASE
#undef STG_A
#undef STG_B

  if (tn < 1024) {
#pragma unroll
    for (int am = 0; am < 8; ++am)
#pragma unroll
      for (int nf = 0; nf < 4; ++nf) {
        int row = tm + wm + (am >> 2) * 64 + (am & 3) * 16 + q4 * 4;
        int col = tn + bn + nf * 16 + lh;
#pragma unroll
        for (int e = 0; e < 4; ++e)
          Kp[(size_t)(row + e) * 1024 + col] = f2bf(acc[am][nf][e]);
      }
  } else {
    __syncthreads();
#pragma unroll
    for (int am = 0; am < 8; ++am)
#pragma unroll
      for (int nf = 0; nf < 4; ++nf) {
        int lrow = wm + (am >> 2) * 64 + (am & 3) * 16 + q4 * 4;
        int lcol = bn + nf * 16 + lh;
        ushort4 v4;
        v4.x = f2bf(acc[am][nf][0]); v4.y = f2bf(acc[am][nf][1]);
        v4.z = f2bf(acc[am][nf][2]); v4.w = f2bf(acc[am][nf][3]);
        *(ushort4*)(lds + lcol * 256 + (lrow ^ ((lcol & 31) << 3))) = v4;
      }
    __syncthreads();
#pragma unroll
    for (int p = 0; p < 16; ++p) {
      int colg = p * 16 + (tid >> 5);
      int jb = tid & 31;
      const unsigned short* src = lds + colg * 256 + ((jb ^ (colg & 31)) << 3);
      *(int4*)(Vt + (size_t)(tn - 1024 + colg) * 16384 + tm + jb * 8) = *(const int4*)src;
    }
  }
}

// ---------- bf16 GEMM 128x64 tile (q-proj, out-proj) ----------
// r12 quad-buffer window (sync per 2 k-steps); r6 T2 swizzle.
__global__ __launch_bounds__(256) void gemm_bt64(
    const unsigned short* __restrict__ A, const unsigned short* __restrict__ B,
    float* __restrict__ Cf, unsigned short* __restrict__ Cb,
    int M, int N, int K, float scale)
{
  __shared__ __attribute__((aligned(16))) unsigned short lds[24576]; // 48 KB
  int w = threadIdx.x >> 6, lane = threadIdx.x & 63;
  int lh = lane & 15, q4 = lane >> 4;
  int tm = blockIdx.y * 128, tn = blockIdx.x * 64;
  int wm = (w & 1) * 64, wn = (w >> 1) * 32;

  int srow = lane >> 2;
  int scol = ((lane & 3) ^ ((lane >> 3) & 3)) << 3;
  int q4s = (q4 ^ ((lh >> 1) & 3)) << 3;

#define STG64(BUF,K0)                                                          \
  {                                                                            \
    _Pragma("unroll") for (int i = 0; i < 2; ++i) {                            \
      int c = w * 2 + i;                                                       \
      cp16(A + (size_t)(tm + c * 16 + srow) * K + (K0) + scol,                 \
           lds + (BUF) * 6144 + c * 512);                                      \
    }                                                                          \
    cp16(B + (size_t)(tn + w * 16 + srow) * K + (K0) + scol,                   \
         lds + (BUF) * 6144 + 4096 + w * 512);                                 \
  }

  f32x4 acc[4][2] = {};
  const int nw = K >> 6;               // windows of 2 k-steps

  STG64(0, 0);
  STG64(1, 32);

  for (int s = 0; s < nw; ++s) {
    __syncthreads();                   // vmcnt(0)+lgkmcnt(0)+s_barrier
    if (s + 1 < nw) {
      STG64((2 * s + 2) & 3, (2 * s + 2) << 5);
      STG64((2 * s + 3) & 3, (2 * s + 3) << 5);
    }
#pragma unroll
    for (int u = 0; u < 2; ++u) {
      const unsigned short* bse = lds + ((2 * s + u) & 3) * 6144;
      bf16x8 afr[4], bfr[2];
#pragma unroll
      for (int r = 0; r < 4; ++r)
        afr[r] = *(const bf16x8*)(bse + (wm + r * 16 + lh) * 32 + q4s);
#pragma unroll
      for (int c = 0; c < 2; ++c)
        bfr[c] = *(const bf16x8*)(bse + 4096 + (wn + c * 16 + lh) * 32 + q4s);
      __builtin_amdgcn_s_setprio(1);
#pragma unroll
      for (int r = 0; r < 4; ++r)
#pragma unroll
        for (int c = 0; c < 2; ++c)
          acc[r][c] = MFMA32(afr[r], bfr[c], acc[r][c]);
      __builtin_amdgcn_s_setprio(0);
    }
  }
#undef STG64

#pragma unroll
  for (int r = 0; r < 4; ++r)
#pragma unroll
    for (int c = 0; c < 2; ++c)
#pragma unroll
      for (int e = 0; e < 4; ++e) {
        int row = tm + wm + r * 16 + q4 * 4 + e;
        int col = tn + wn + c * 16 + lh;
        if (Cb) Cb[(size_t)row * N + col] = f2bf(acc[r][c][e] * scale);
        else    Cf[(size_t)row * N + col] = acc[r][c][e] * scale;
      }
}

// ---------- attention — r17: 2-way split (r16's 4-way reverted: occupancy
// did NOT rise, WRITE_SIZE doubled, dur +6%) + bias-init + HW bf16 convert.
// VALU diagnosis: VALUBusy 50% >> MfmaUtil 28%; per-(s,c) softmax ~20 VALU
// of which 12 = manual f2bf bit-twiddle. (__bf16) fptrunc cast -> compiler
// emits v_cvt_pk_bf16_f32 pairs (RNE, bit-identical); no inline asm (r15's
// NaN lesson).
__global__ __launch_bounds__(256) void attn_kernel(
    const unsigned short* __restrict__ Q, const unsigned short* __restrict__ Kp,
    const unsigned short* __restrict__ VT, const float* __restrict__ bz,
    float* __restrict__ po, float* __restrict__ lp)
{
  __shared__ __attribute__((aligned(16))) unsigned short Klds[8192]; // 2 bufs
  __shared__ __attribute__((aligned(16))) unsigned short Vlds[8192]; // 2 bufs
  int w = threadIdx.x >> 6, lane = threadIdx.x & 63;
  int lh = lane & 15, q4 = lane >> 4;

  // XCD swizzle: same-bh blocks land on same XCD (bh & 7 == xcd)
  int id = blockIdx.x;
  int xcd = id & 7, j = id >> 3;
  int ql = j & 7;                   // 8 blocks per bh
  int half = ql & 1, qt = ql >> 1;  // token half, q-tile
  int bh = (j >> 3) * 8 + xcd;
  int b = bh >> 4, h = bh & 15;
  int q0 = qt * 128;
  int t00 = half * 2048;

  const unsigned short* Qb = Q + (size_t)(b * 512 + q0 + w * 32) * 1024 + h * 64;
  const unsigned short* Kb = Kp + (size_t)(b * 4096) * 1024 + h * 64;
  const unsigned short* Vb = VT + (size_t)(h * 64) * 16384 + b * 4096;
  const float* bzg = bz + (size_t)b * 4096;

  // Q B-operand fragments: 2 strips of 16 q-rows
  bf16x8 bq[2][2];
#pragma unroll
  for (int s = 0; s < 2; ++s)
#pragma unroll
    for (int th = 0; th < 2; ++th)
      bq[s][th] = *(const bf16x8*)(Qb + (size_t)(s * 16 + lh) * 1024 + th * 32 + q4 * 8);

  f32x4 oa[2][4] = {};              // O^T accumulators [strip][d-tile]
  float ls[2] = {0.f, 0.f};

  int rl = lane >> 3, blk = lane & 7;
  int sw = ((blk ^ rl) * 8);        // xor-swizzled 8-ushort block offset in source row

  // prologue: stage tile 0 into buf 0
  {
    int t = t00;
#pragma unroll
    for (int r = 0; r < 2; ++r) {
      int seg = r * 4 + w;
      int row = seg * 8 + rl;
      cp16(Kb + (size_t)(t + row) * 1024 + sw, Klds + seg * 512);
      cp16(Vb + (size_t)row * 16384 + t + sw, Vlds + seg * 512);
    }
  }

  for (int ti = 0; ti < 32; ++ti) {
    int t = t00 + ti * 64;
    __syncthreads();                 // vmcnt(0)+lgkmcnt(0)+s_barrier
    if (ti < 31) {
      int t2 = t + 64;
      int bo2 = ((ti + 1) & 1) * 4096;
#pragma unroll
      for (int r = 0; r < 2; ++r) {
        int seg = r * 4 + w;
        int row = seg * 8 + rl;
        cp16(Kb + (size_t)(t2 + row) * 1024 + sw, Klds + bo2 + seg * 512);
        cp16(Vb + (size_t)row * 16384 + t2 + sw, Vlds + bo2 + seg * 512);
      }
    }
    const unsigned short* Kl = Klds + (ti & 1) * 4096;
    const unsigned short* Vl = Vlds + (ti & 1) * 4096;

    // bias (pre-transformed) for this tile's tokens
    float4 bz4[4];
#pragma unroll
    for (int c = 0; c < 4; ++c)
      bz4[c] = *(const float4*)(bzg + t + c * 16 + q4 * 4);

    // K fragments: A[m=tok][k=d], lane m=lh, k=th*32+q4*8..+8
    bf16x8 kf[4][2];
#pragma unroll
    for (int c = 0; c < 4; ++c)
#pragma unroll
      for (int th = 0; th < 2; ++th)
        kf[c][th] = *(const bf16x8*)(Kl + (c * 16 + lh) * 64 + (((th << 2) + q4) ^ (lh & 7)) * 8);
    // V fragments: A[m=d][k=tok], lane m=lh (+c2*16), k=c*16+q4*4..+4
    bf16x4 vf[4][4];
#pragma unroll
    for (int c = 0; c < 4; ++c)
#pragma unroll
      for (int c2 = 0; c2 < 4; ++c2)
        vf[c][c2] = *(const bf16x4*)(Vl + (c2 * 16 + lh) * 64 +
                                     (((c << 1) + (q4 >> 1)) ^ (lh & 7)) * 8 + (q4 & 1) * 4);

#pragma unroll
    for (int s = 0; s < 2; ++s) {
#pragma unroll
      for (int c = 0; c < 4; ++c) {
        // bias-init accumulator: z = bias (element e = token q4*4+e of group c)
        f32x4 z = {bz4[c].x, bz4[c].y, bz4[c].z, bz4[c].w};
        z = MFMA32(kf[c][0], bq[s][0], z);
        z = MFMA32(kf[c][1], bq[s][1], z);
        float p0 = __builtin_amdgcn_exp2f(z[0]);
        float p1 = __builtin_amdgcn_exp2f(z[1]);
        float p2 = __builtin_amdgcn_exp2f(z[2]);
        float p3 = __builtin_amdgcn_exp2f(z[3]);
        ls[s] += (p0 + p1) + (p2 + p3);
        bf16x4 pb;
        pb[0] = f2bf_hw(p0); pb[1] = f2bf_hw(p1);
        pb[2] = f2bf_hw(p2); pb[3] = f2bf_hw(p3);
#pragma unroll
        for (int c2 = 0; c2 < 4; ++c2)
          oa[s][c2] = MFMA16(vf[c][c2], pb, oa[s][c2]);
      }
    }
  }

  // l: lane holds partial for q=lh; reduce across the 4 q4 groups
#pragma unroll
  for (int s = 0; s < 2; ++s) {
    ls[s] += __shfl_xor(ls[s], 16);
    ls[s] += __shfl_xor(ls[s], 32);
  }

  // partial stores: po[half*256 + bh*4+qt][d=64][q=128]
  int sl = bh * 4 + qt;
  float* pslice = po + (size_t)(half * 256 + sl) * 8192;
#pragma unroll
  for (int s = 0; s < 2; ++s) {
    if (q4 == 0) lp[half * 32768 + sl * 128 + w * 32 + s * 16 + lh] = ls[s];
#pragma unroll
    for (int c2 = 0; c2 < 4; ++c2)
#pragma unroll
      for (int e = 0; e < 4; ++e)
        pslice[(c2 * 16 + q4 * 4 + e) * 128 + w * 32 + s * 16 + lh] = oa[s][c2][e];
  }
}

// ---------- merge token-half partials, normalize, pack to bf16 ao ----------
__global__ void norm_kernel(const float* __restrict__ po, const float* __restrict__ lp,
                            unsigned short* __restrict__ ao) {
  int g = blockIdx.x * 256 + threadIdx.x;   // 262144 threads
  int d8 = (g & 7) * 8;
  int rowid = g >> 3;                        // 0..32767 = bh*512 + qt*128 + qcol
  int bh = rowid >> 9, rq = rowid & 511, qt = rq >> 7, qcol = rq & 127;
  int sl = bh * 4 + qt;
  const float* p0 = po + (size_t)sl * 8192;
  const float* p1 = po + (size_t)(256 + sl) * 8192;
  float l = lp[sl * 128 + qcol] + lp[32768 + sl * 128 + qcol];
  float inv = 1.f / l;
  unsigned short o8[8];
#pragma unroll
  for (int k = 0; k < 8; ++k)
    o8[k] = f2bf((p0[(d8 + k) * 128 + qcol] + p1[(d8 + k) * 128 + qcol]) * inv);
  int b = bh >> 4, h = bh & 15;
  unsigned short* dst = ao + (size_t)(b * 512 + qt * 128 + qcol) * 1024 + h * 64 + d8;
  *(ushort4*)dst = *(ushort4*)o8;
  *(ushort4*)(dst + 4) = *(ushort4*)(o8 + 4);
}

// ---------- launch ----------
extern "C" void kernel_launch(void* const* d_in, const int* in_sizes, int n_in,
                              void* d_out, int out_size, void* d_ws, size_t ws_size,
                              hipStream_t stream) {
  const float* query  = (const float*)d_in[0];
  const float* memory = (const float*)d_in[1];
  const float* bias   = (const float*)d_in[2];
  const float* Wq     = (const float*)d_in[3];
  const float* Wk     = (const float*)d_in[4];
  const float* Wv     = (const float*)d_in[5];
  const float* Wo     = (const float*)d_in[6];
  float* out = (float*)d_out;

  unsigned short* ws  = (unsigned short*)d_ws;
  unsigned short* qbf = ws;                       // 2048*1024
  unsigned short* mbf = qbf + 2097152;            // 16384*1024
  unsigned short* WqT = mbf + 16777216;           // 4 x 1024*1024 contiguous
  unsigned short* WkT = WqT + 1048576;
  unsigned short* WvT = WkT + 1048576;
  unsigned short* WoT = WvT + 1048576;
  unsigned short* qp  = WoT + 1048576;            // 2048*1024 (scaled q proj)
  unsigned short* kp  = qp + 2097152;             // 16384*1024
  unsigned short* vT  = kp + 16777216;            // 1024*16384
  unsigned short* ao  = vT + 16777216;            // 2048*1024
  float* bzw = (float*)(ao + 2097152);            // 16384 floats (bias*log2e-16)
  // po/lp alias qbf+mbf (dead after the projection GEMMs)
  float* po = (float*)ws;                         // 512 slices x 8192 floats = 16 MB
  float* lp = po + 4194304;                       // 65536 floats

  conv_both<<<18448, 256, 0, stream>>>(query, memory, bias, qbf, mbf, bzw);
  transpose4<<<dim3(32, 32, 4), dim3(32, 8), 0, stream>>>(Wq, Wk, Wv, Wo, WqT);

  // q = (query@Wq) * (1/8)*log2e   [2048 x 1024]
  gemm_bt64<<<dim3(16, 16), 256, 0, stream>>>(qbf, WqT, nullptr, qp, 2048, 1024, 1024, 0.125f * LOG2E);
  // fused: kp = memory@Wk, vT = (memory@Wv)^T — one 16384x2048x1024 GEMM
  gemm_kv<<<512, 512, 0, stream>>>(mbf, WkT, kp, vT);

  attn_kernel<<<512, 256, 0, stream>>>(qp, kp, vT, bzw, po, lp);
  norm_kernel<<<1024, 256, 0, stream>>>(po, lp, ao);

  // out = ao @ Wo (fp32 out)
  gemm_bt64<<<dim3(16, 16), 256, 0, stream>>>(ao, WoT, out, nullptr, 2048, 1024, 1024, 1.f);
}